// Round 10
// baseline (483.160 us; speedup 1.0000x reference)
//
#include <hip/hip_runtime.h>
#include <cstdint>

// Problem constants
#define BB 2
#define TT 5
#define CC 64
#define HH 128
#define WW 128
#define GG 8
#define KKD 9
#define OFFC 144
#define H2 64
#define W2 64
#define TCF 2
#define HW (HH*WW)
#define HW2 (H2*W2)
#define PLANE1 278784  // 132*132*16 shorts (full-res padded NHWC chunk plane)
#define PLANE0 69696   // 66*66*16 shorts (half-res padded NHWC chunk plane)

typedef __attribute__((ext_vector_type(4))) short short4v;
typedef __attribute__((ext_vector_type(8))) short short8;
typedef __attribute__((ext_vector_type(4))) float floatx4;
typedef __attribute__((ext_vector_type(16))) float floatx16;

static __device__ __forceinline__ unsigned short f2bf(float f) {
    unsigned int u = __float_as_uint(f);
    unsigned int r = (u + 0x7fffu + ((u >> 16) & 1u)) >> 16;
    return (unsigned short)r;
}

typedef __attribute__((address_space(1))) const unsigned int g_u32;
typedef __attribute__((address_space(3))) unsigned int l_u32;
static __device__ __forceinline__ void async16(const short* g, short* l) {
    __builtin_amdgcn_global_load_lds((g_u32*)g, (l_u32*)l, 16, 0, 0);
}

// ---------------- dconv weight swizzle into MFMA B-fragment order (bf16) -------------
// layout: [chunk(36)][tile(2)][lane(64)][j(8)]
__global__ void wswzD_k(const float* __restrict__ w, short* __restrict__ ws) {
    int idx = blockIdx.x * 256 + threadIdx.x;
    if (idx >= 36864) return;
    int j = idx & 7;
    int lane = (idx >> 3) & 63;
    int tile = (idx >> 9) & 1;
    int chunk = idx >> 10;
    int ck = chunk * 16 + (lane >> 5) * 8 + j;
    int oc = tile * 32 + (lane & 31);
    int cin = ck / 9;
    int kt = ck - cin * 9;
    ws[idx] = (short)f2bf(w[((size_t)oc * 64 + cin) * 9 + kt]);
}

// ---------------- conv weight swizzle into MFMA fragment order (bf16) ----------------
// layout: [chunk(8)][tap(TAPS)][ocF(5)][lane(64)][j(8)]
template <int TAPS>
__global__ void wswz_k(const float* __restrict__ w, short* __restrict__ ws) {
    int idx = blockIdx.x * 256 + threadIdx.x;
    if (idx >= 8 * TAPS * 5 * 512) return;
    int jj = idx & 7;
    int lane = (idx >> 3) & 63;
    int rest = idx >> 9;
    int ocF = rest % 5;
    int ct = rest / 5;
    int tap = ct % TAPS;
    int chunk = ct / TAPS;
    int oc = ocF * 32 + (lane & 31);
    int cin = chunk * 16 + (lane >> 5) * 8 + jj;
    float v = 0.f;
    if (oc < OFFC) v = w[((size_t)oc * 128 + cin) * TAPS + tap];
    ws[idx] = (short)f2bf(v);
}

// ---------------- 2x2 average pool -> padded NHWC-bf16 chunk planes ----------------
__global__ void avgpool_k(const float* __restrict__ x, short* __restrict__ x2T) {
    __shared__ float sL[64 * 17];
    const int h2 = blockIdx.x;
    const int chunk = blockIdx.y;
    const int img = blockIdx.z;
    const int tid = threadIdx.x;
    const float* base = x + ((size_t)img * 64 + chunk * 16) * HW + (size_t)(2 * h2) * WW;
#pragma unroll
    for (int it = 0; it < 4; ++it) {
        int e = it * 256 + tid;
        int cin = e >> 6, w2 = e & 63;
        const float* sp = base + (size_t)cin * HW + 2 * w2;
        sL[w2 * 17 + cin] = 0.25f * (sp[0] + sp[1] + sp[WW] + sp[WW + 1]);
    }
    __syncthreads();
    int w2 = tid >> 2, cg = tid & 3;
    short4v sv;
#pragma unroll
    for (int q = 0; q < 4; ++q) sv[q] = (short)f2bf(sL[w2 * 17 + cg * 4 + q]);
    *(short4v*)&x2T[((size_t)img * 4 + chunk) * PLANE0 +
                    ((size_t)(h2 + 1) * 66 + (w2 + 1)) * 16 + cg * 4] = sv;
}

// ---------------- center-frame transpose -> padded NHWC-bf16 chunk planes ------------
__global__ void xtrans_k(const float* __restrict__ x, short* __restrict__ xT) {
    __shared__ float sL[128 * 17];
    const int row = blockIdx.x;
    const int chunk = blockIdx.y;
    const int b = blockIdx.z;
    const int tid = threadIdx.x;
    const float* base = x + ((size_t)(b * 5 + TCF) * 64 + chunk * 16) * HW + (size_t)row * WW;
#pragma unroll
    for (int it = 0; it < 8; ++it) {
        int e = it * 256 + tid;
        int cin = e >> 7, col = e & 127;
        sL[col * 17 + cin] = base[(size_t)cin * HW + col];
    }
    __syncthreads();
    int col = tid >> 1, half = tid & 1;
    short8 sv;
#pragma unroll
    for (int q = 0; q < 8; ++q) sv[q] = (short)f2bf(sL[col * 17 + half * 8 + q]);
    *(short8*)&xT[((size_t)b * 4 + chunk) * PLANE1 +
                  ((size_t)(row + 2) * 132 + (col + 2)) * 16 + half * 8] = sv;
}

// ---------------- non-center frames -> group-major NHWC fp32 for dconv gather --------
// xg layout: [bj(8)][g(8)][H*W][8ch] fp32.  One corner sample = 32B contiguous.
__global__ void xgt_k(const float* __restrict__ x, float* __restrict__ xg) {
    __shared__ float sL[128 * 9];
    const int row = blockIdx.x;   // 0..127
    const int g = blockIdx.y;     // 0..7
    const int bj = blockIdx.z;    // 0..7
    const int b = bj >> 2;
    const int j = bj & 3;
    const int i = j + (j >= 2 ? 1 : 0);
    const int tid = threadIdx.x;
    const float* base = x + ((size_t)(b * TT + i) * CC + g * 8) * HW + (size_t)row * WW;
#pragma unroll
    for (int it = 0; it < 4; ++it) {
        int e = it * 256 + tid;
        int cin = e >> 7, col = e & 127;
        sL[col * 9 + cin] = base[(size_t)cin * HW + col];
    }
    __syncthreads();
    int col = tid >> 1, half = tid & 1;
    floatx4 v;
#pragma unroll
    for (int q = 0; q < 4; ++q) v[q] = sL[col * 9 + half * 4 + q];
    *(floatx4*)&xg[(((size_t)(bj * 8 + g) * HW + row * WW + col) << 3) + half * 4] = v;
}

// ---------------- MODE 0: 3x3 half-res conv, round-2 configuration ------------------
static __device__ __forceinline__ void conv0_body(
    const short* __restrict__ srcAT,
    const short* __restrict__ wswz, const float* __restrict__ bias,
    float* __restrict__ out) {
    constexpr int KS = 3;
    constexpr int IM = 64;
    constexpr int PD = IM + KS - 1;
    constexpr int TAPS = KS * KS;
    constexpr int OROWS = 4;
    constexpr int SROWS = OROWS + KS - 1;
    constexpr int PLANE = PD * PD * 16;
    constexpr int SLAB16 = SROWS * PD * 2;
    constexpr int BUFSH = SROWS * PD * 16;

    extern __shared__ __align__(16) short stg[];  // 2 * BUFSH shorts

    const int bj = blockIdx.z;
    const int b = bj >> 2;
    const int j = bj & 3;
    const int i = j + (j >= 2 ? 1 : 0);
    const int y0 = blockIdx.x * OROWS;
    const int tid = threadIdx.x;
    const int wave = tid >> 6;
    const int lane = tid & 63;
    const int l31 = lane & 31;
    const int quad = lane >> 5;
    const int wrb = wave >> 1;
    const int wc0 = (wave & 1) * 32;

    const short* srcA = srcAT + (size_t)((b * 5 + i) * 4) * PLANE;
    const short* srcB = srcAT + (size_t)((b * 5 + TCF) * 4) * PLANE;

    floatx16 acc[5];
#pragma unroll
    for (int o = 0; o < 5; ++o)
#pragma unroll
        for (int g = 0; g < 16; ++g) acc[o][g] = 0.f;

    auto stage = [&](int c, int sIdx) {
        const short* plane = (c < 4) ? (srcA + (size_t)c * PLANE)
                                     : (srcB + (size_t)(c - 4) * PLANE);
        const short* srcRow = plane + (size_t)y0 * (PD * 16);
        short* dst = stg + (size_t)sIdx * BUFSH;
        for (int base = wave * 64; base < SLAB16; base += 512) {
            int b2 = min(base, SLAB16 - 64);
            async16(srcRow + (size_t)(b2 + lane) * 8, dst + (size_t)b2 * 8);
        }
    };

    stage(0, 0);
    for (int c = 0; c < 8; ++c) {
        __syncthreads();
        if (c < 7) stage(c + 1, (c + 1) & 1);
        const short* sbuf = stg + (size_t)(c & 1) * BUFSH;
        const short* wpc = wswz + (size_t)c * TAPS * 2560 + lane * 8;
#pragma unroll 5
        for (int tap = 0; tap < TAPS; ++tap) {
            const int ky = tap / KS, kx = tap - ky * KS;
            short8 wf[5];
            const short* wp = wpc + (size_t)tap * 2560;
#pragma unroll
            for (int o = 0; o < 5; ++o) wf[o] = *(const short8*)(wp + o * 512);
            short8 pf = *(const short8*)(sbuf +
                ((size_t)(wrb + ky) * PD + (wc0 + kx + l31)) * 16 + quad * 8);
#pragma unroll
            for (int o = 0; o < 5; ++o)
                acc[o] = __builtin_amdgcn_mfma_f32_32x32x16_bf16(wf[o], pf, acc[o], 0, 0, 0);
        }
    }

    const size_t imgBase = (size_t)bj * OFFC * (IM * IM);
    const size_t rowAddr = imgBase + (size_t)(y0 + wrb) * IM + wc0 + l31;
#pragma unroll
    for (int o = 0; o < 5; ++o) {
        const int rmax = (o == 4) ? 8 : 16;
#pragma unroll
        for (int r = 0; r < 16; ++r) {
            if (r >= rmax) break;
            int oc = o * 32 + (r & 3) + 8 * (r >> 2) + 4 * quad;
            float v = acc[o][r] + bias[oc];
            out[rowAddr + (size_t)oc * (IM * IM)] = v;
        }
    }
}

__global__ __launch_bounds__(512) void convmf0_k(
    const short* __restrict__ srcAT,
    const short* __restrict__ wswz, const float* __restrict__ bias,
    float* __restrict__ out) {
    conv0_body(srcAT, wswz, bias, out);
}

// ---------------- MODE 1: 5x5 conv, LDS weights + o-split + FR=2 cols ---------------
// Round 9 (8 waves x [5 wf + 1 pf] from LDS) sits ON its LDS-read roofline:
// 96 reads vs 80 MFMA per CU-tap -> cap 56%, measured 54.7%. This round cuts
// reads/MFMA: ocF split over blockIdx.y ({0,1,2} / {3,4}), 256-thr blocks (4 waves),
// FR=2 column fragments -> per wave per tap: OCNT wf + 2 pf reads, 2*OCNT MFMAs
// (y=0: 5 reads/6 MFMA = 0.83 vs 1.2) -> cap ~80%.
// Register model (rounds 4-6 lesson): budget is VGPR+AGPR <= 256 at 2 waves/EU,
// <= ~170 at 3. acc = 2*OCNT*16 = 96 AGPR + ~70 VGPR = 166 <= 256 with
// waves_per_eu(2,2). LDS = pixel dbuf 50688 + weight-piece dbuf 18432 = 69120 B
// -> 2 blocks/CU. Weights staged in 9 pieces (<=3 taps, o-slice only).
template <int OCNT, int OBASE>
static __device__ __forceinline__ void conv1_body(
    const short* __restrict__ srcAT, const short* __restrict__ srcBT,
    const short* __restrict__ wswz, const float* __restrict__ bias,
    const float* __restrict__ addend, float* __restrict__ out) {
    constexpr int KS = 5;
    constexpr int IM = 128;
    constexpr int PD = IM + KS - 1;          // 132
    constexpr int OROWS = 2;
    constexpr int SROWS = OROWS + KS - 1;    // 6
    constexpr int PLANE = PD * PD * 16;
    constexpr int SLAB16 = SROWS * PD * 2;   // 1584 16B-units
    constexpr int BUFSH = SROWS * PD * 16;   // 12672 shorts per pixel buffer
    constexpr int WP = 3 * 3 * 512;          // 4608 shorts piece buffer (max slice)

    extern __shared__ __align__(16) short lds[];  // 2*BUFSH + 2*WP shorts
    short* pbuf = lds;
    short* wbuf = lds + 2 * BUFSH;

    const int bj = blockIdx.z;
    const int b = bj >> 2;
    const int y0 = blockIdx.x * OROWS;
    const int tid = threadIdx.x;
    const int wave = tid >> 6;
    const int lane = tid & 63;
    const int l31 = lane & 31;
    const int quad = lane >> 5;
    const int wrb = wave >> 1;             // row 0..1
    const int wc0 = (wave & 1) * 64;       // col-pair base

    const short* srcA = srcAT + (size_t)(bj * 4) * PLANE;
    const short* srcB = srcBT + (size_t)(b * 4) * PLANE;

    floatx16 acc[2][OCNT];
#pragma unroll
    for (int f = 0; f < 2; ++f)
#pragma unroll
        for (int o = 0; o < OCNT; ++o)
#pragma unroll
            for (int g = 0; g < 16; ++g) acc[f][o][g] = 0.f;

    auto stageP = [&](int c, int sIdx) {
        const short* plane = (c < 4) ? (srcA + (size_t)c * PLANE)
                                     : (srcB + (size_t)(c - 4) * PLANE);
        const short* srcRow = plane + (size_t)y0 * (PD * 16);
        short* dst = pbuf + (size_t)sIdx * BUFSH;
        for (int base = wave * 64; base < SLAB16; base += 256) {
            int b2 = min(base, SLAB16 - 64);
            async16(srcRow + (size_t)(b2 + lane) * 8, dst + (size_t)b2 * 8);
        }
    };
    // stage o-slice [OBASE, OBASE+OCNT) of taps [qoff, qoff+qn) of chunk c.
    // 16B units: per tap full = 320 (5 o x 64 lanes); slice = OCNT*64 units.
    // Runs are 64-aligned and 64 | OCNT*64, so a run never straddles a tap.
    auto stageW = [&](int c, int qoff, int qn, int sIdx) {
        const short* src = wswz + (size_t)c * 64000;
        short* dst = wbuf + (size_t)sIdx * WP;
        const int n16 = qn * OCNT * 64;
        for (int base = wave * 64; base < n16; base += 256) {
            int b2 = min(base, n16 - 64);
            int u = b2 + lane;
            int tp = u / (OCNT * 64);
            int wi = u - tp * (OCNT * 64);
            async16(src + ((size_t)(qoff + tp) * 320 + OBASE * 64 + wi) * 8,
                    dst + (size_t)u * 8);
        }
    };

    constexpr int NP = 9;
    constexpr int QOFF[NP] = {0, 3, 6, 9, 12, 15, 18, 21, 24};
    constexpr int QN[NP] = {3, 3, 3, 3, 3, 3, 3, 3, 1};

    stageP(0, 0);
    stageW(0, 0, 3, 0);
    for (int c = 0; c < 8; ++c) {
#pragma unroll
        for (int q = 0; q < NP; ++q) {
            __syncthreads();  // wbuf[(c+q)&1] ready; other half free; q0: pbuf[c&1] ready
            const int pb = (c + q) & 1;  // piece parity (NP odd -> alternates cleanly)
            if (!(c == 7 && q == NP - 1)) {
                const int nc = (q == NP - 1) ? c + 1 : c;
                const int nq = (q == NP - 1) ? 0 : q + 1;
                stageW(nc, QOFF[nq], QN[nq], pb ^ 1);
            }
            if (q == 0 && c < 7) stageP(c + 1, (c + 1) & 1);
            const short* sbuf = pbuf + (size_t)(c & 1) * BUFSH;
            const short* wb = wbuf + (size_t)pb * WP + lane * 8;
#pragma unroll
            for (int t = 0; t < QN[q]; ++t) {
                const int tap = QOFF[q] + t;
                const int ky = tap / KS, kx = tap - ky * KS;
                short8 wf[OCNT];
#pragma unroll
                for (int o = 0; o < OCNT; ++o)
                    wf[o] = *(const short8*)(wb + (t * OCNT + o) * 512);
                short8 pf[2];
#pragma unroll
                for (int f = 0; f < 2; ++f)
                    pf[f] = *(const short8*)(sbuf +
                        ((size_t)(wrb + ky) * PD + (wc0 + f * 32 + kx + l31)) * 16 +
                        quad * 8);
#pragma unroll
                for (int o = 0; o < OCNT; ++o)
#pragma unroll
                    for (int f = 0; f < 2; ++f)
                        acc[f][o] = __builtin_amdgcn_mfma_f32_32x32x16_bf16(
                            wf[o], pf[f], acc[f][o], 0, 0, 0);
            }
        }
    }

    const size_t imgBase = (size_t)bj * OFFC * (IM * IM);
#pragma unroll
    for (int f = 0; f < 2; ++f) {
        const size_t rowAddr = imgBase + (size_t)(y0 + wrb) * IM + wc0 + f * 32 + l31;
#pragma unroll
        for (int o = 0; o < OCNT; ++o) {
            const int rmax = ((OBASE + o) == 4) ? 8 : 16;
#pragma unroll
            for (int r = 0; r < 16; ++r) {
                if (r >= rmax) break;
                int oc = (OBASE + o) * 32 + (r & 3) + 8 * (r >> 2) + 4 * quad;
                float v = acc[f][o][r] + bias[oc];
                size_t a = rowAddr + (size_t)oc * (IM * IM);
                out[a] = v + addend[a];
            }
        }
    }
}

__global__ __launch_bounds__(256)
__attribute__((amdgpu_waves_per_eu(2, 2))) void convmf1_k(
    const short* __restrict__ srcAT, const short* __restrict__ srcBT,
    const short* __restrict__ wswz, const float* __restrict__ bias,
    const float* __restrict__ addend, float* __restrict__ out) {
    if (blockIdx.y == 0)
        conv1_body<3, 0>(srcAT, srcBT, wswz, bias, addend, out);
    else
        conv1_body<2, 3>(srcAT, srcBT, wswz, bias, addend, out);
}

// ---------------- bilinear 2x upsample * 2.0 ----------------
__global__ void upsample_k(const float* __restrict__ off2, float* __restrict__ off2u) {
    int idx = blockIdx.x * 256 + threadIdx.x;  // < 18874368
    int ox = idx & 127;
    int oy = (idx >> 7) & 127;
    int p = idx >> 14;
    const float* sp = off2 + (size_t)p * HW2;
    float sy = 0.5f * oy - 0.25f;
    float sx = 0.5f * ox - 0.25f;
    float y0f = floorf(sy), x0f = floorf(sx);
    int y0 = (int)y0f, x0 = (int)x0f;
    float fy = sy - y0f, fx = sx - x0f;
    int y0c = max(y0, 0), y1c = min(y0 + 1, 63);
    int x0c = max(x0, 0), x1c = min(x0 + 1, 63);
    float v00 = sp[y0c * 64 + x0c], v01 = sp[y0c * 64 + x1c];
    float v10 = sp[y1c * 64 + x0c], v11 = sp[y1c * 64 + x1c];
    float v = v00 * (1.f - fy) * (1.f - fx) + v01 * (1.f - fy) * fx +
              v10 * fy * (1.f - fx) + v11 * fy * fx;
    off2u[idx] = 2.0f * v;
}

// ---------------- deformable conv (3x3, G=8 offset groups), MFMA phase B -------------
// block = 256 thr (4 waves) per 32-px row segment. XCD-pinned: bj = blockIdx.x (%8
// round-robin over XCDs) so each image's 4MB gather footprint stays in one L2.
// Phase A gathers from xg (group-major NHWC fp32): one corner = 2x float4 (32B
// contiguous). Taps processed in 3 groups of 3 (unroll 1 outer) to bound the
// scheduler's hoist window at 24 float4 loads; amdgpu_waves_per_eu(4,4) grants the
// full 128-VGPR budget (LDS caps us at 4 blocks/CU anyway) -> no scratch spill.
#define SROW 584
__global__ __launch_bounds__(256)
__attribute__((amdgpu_waves_per_eu(4, 4))) void dconv_k(
    const float* __restrict__ xg,   // (8 imgs, G, H*W, 8ch) fp32
    const float* __restrict__ off,  // (BJ,144,H,W)
    const short* __restrict__ wsw,  // swizzled B-frags [chunk36][tile2][lane64][8]
    float* __restrict__ out, short* __restrict__ z1T, int outMode) {
    const int bj = blockIdx.x;   // image -> XCD (round-robin by linear block ID)
    const int b = bj >> 2;
    const int j = bj & 3;
    const int i = j + (j >= 2 ? 1 : 0);
    const int seg = blockIdx.y;  // 0..511
    const int y = seg >> 2;
    const int x0 = (seg & 3) << 5;
    const int tid = threadIdx.x;

    __shared__ short sS[32 * SROW];  // 37376 B; reused as float Pbuf[4][32][33]
    float* Pbuf = (float*)sS;

    const float* offp = off + (size_t)bj * OFFC * HW + y * WW + x0;

    // ---- phase A: bilinear sampling into LDS ----
    {
        const int g = tid >> 5;   // 0..7 offset group
        const int px = tid & 31;
        short* srow = sS + px * SROW + g * 72;
        const float* xgp = xg + ((size_t)(bj * 8 + g)) * ((size_t)HW * 8);
        const float* offg = offp + (size_t)(g * 18) * HW + px;
#pragma unroll 1
        for (int kg = 0; kg < 3; ++kg) {
            const int kyy = kg - 1;
            const float fyrow = (float)(y + kyy);
#pragma unroll
            for (int kk = 0; kk < 3; ++kk) {
                const int k = kg * 3 + kk;
                float dy = offg[(size_t)(k * 2) * HW];
                float dx = offg[(size_t)(k * 2 + 1) * HW];
                const int kxx = kk - 1;
                float sy = fyrow + dy;
                float sx = (float)(x0 + px + kxx) + dx;
                float y0f = floorf(sy), x0f = floorf(sx);
                int iy = (int)y0f, ix = (int)x0f;
                float wy = sy - y0f, wx = sx - x0f;
                bool yv0 = (iy >= 0) & (iy < HH);
                bool yv1 = (iy + 1 >= 0) & (iy + 1 < HH);
                bool xv0 = (ix >= 0) & (ix < WW);
                bool xv1 = (ix + 1 >= 0) & (ix + 1 < WW);
                float w00 = (yv0 && xv0) ? (1.f - wy) * (1.f - wx) : 0.f;
                float w01 = (yv0 && xv1) ? (1.f - wy) * wx : 0.f;
                float w10 = (yv1 && xv0) ? wy * (1.f - wx) : 0.f;
                float w11 = (yv1 && xv1) ? wy * wx : 0.f;
                int iy0 = min(max(iy, 0), HH - 1);
                int iy1 = min(max(iy + 1, 0), HH - 1);
                int ix0 = min(max(ix, 0), WW - 1);
                int ix1 = min(max(ix + 1, 0), WW - 1);
                const float* p00 = xgp + ((size_t)(iy0 * WW + ix0) << 3);
                const float* p01 = xgp + ((size_t)(iy0 * WW + ix1) << 3);
                const float* p10 = xgp + ((size_t)(iy1 * WW + ix0) << 3);
                const float* p11 = xgp + ((size_t)(iy1 * WW + ix1) << 3);
                floatx4 a00 = *(const floatx4*)p00, b00 = *(const floatx4*)(p00 + 4);
                floatx4 a01 = *(const floatx4*)p01, b01 = *(const floatx4*)(p01 + 4);
                floatx4 a10 = *(const floatx4*)p10, b10 = *(const floatx4*)(p10 + 4);
                floatx4 a11 = *(const floatx4*)p11, b11 = *(const floatx4*)(p11 + 4);
#pragma unroll
                for (int c = 0; c < 4; ++c) {
                    float v = a00[c] * w00 + a01[c] * w01 + a10[c] * w10 + a11[c] * w11;
                    srow[c * 9 + k] = (short)f2bf(v);
                    float v2 = b00[c] * w00 + b01[c] * w01 + b10[c] * w10 + b11[c] * w11;
                    srow[(c + 4) * 9 + k] = (short)f2bf(v2);
                }
            }
        }
    }
    __syncthreads();

    // ---- phase B: C[px 32][oc 64] = S * W, K=576, MFMA 32x32x16 ----
    const int wv = tid >> 6;      // wave 0..3
    const int lane = tid & 63;
    const int tile = wv >> 1;     // oc tile
    const int kw = wv & 1;        // K half
    floatx16 acc;
#pragma unroll
    for (int g = 0; g < 16; ++g) acc[g] = 0.f;

    const short* aBase = sS + (lane & 31) * SROW + (lane >> 5) * 8;
    const short* bBase = wsw + ((size_t)tile * 64 + lane) * 8;
    for (int chunk = kw * 18; chunk < kw * 18 + 18; ++chunk) {
        short8 af = *(const short8*)(aBase + chunk * 16);
        short8 bf = *(const short8*)(bBase + (size_t)chunk * 1024);
        acc = __builtin_amdgcn_mfma_f32_32x32x16_bf16(af, bf, acc, 0, 0, 0);
    }

    __syncthreads();  // all waves done reading sS; alias as Pbuf
    {
        const int n = lane & 31;
#pragma unroll
        for (int g = 0; g < 16; ++g) {
            int m = (g & 3) + 8 * (g >> 2) + 4 * (lane >> 5);
            Pbuf[wv * 1056 + m * 33 + n] = acc[g];
        }
    }
    __syncthreads();

    // ---- epilogue: reduce K-halves, store ----
    if (outMode == 0) {
        const int chunk = tid >> 6;
        const int px = (tid >> 1) & 31;
        const int half = tid & 1;
        const int t2 = chunk >> 1;
        const int n0 = (chunk & 1) * 16 + half * 8;
        short8 sv;
#pragma unroll
        for (int q = 0; q < 8; ++q) {
            float v = Pbuf[(t2 * 2) * 1056 + px * 33 + n0 + q] +
                      Pbuf[(t2 * 2 + 1) * 1056 + px * 33 + n0 + q];
            sv[q] = (short)f2bf(v);
        }
        *(short8*)&z1T[((size_t)bj * 4 + chunk) * PLANE1 +
                       ((size_t)(y + 2) * 132 + (x0 + 2 + px)) * 16 + half * 8] = sv;
    } else {
        const size_t planeBase = (size_t)(b * TT + i) * CC * HW;
        const size_t rowBase = planeBase + (size_t)y * WW + x0;
#pragma unroll
        for (int rep = 0; rep < 8; ++rep) {
            int elem = rep * 256 + tid;
            int oc = elem >> 5;
            int px = elem & 31;
            int t = oc >> 5;
            int n = oc & 31;
            float v = Pbuf[(t * 2) * 1056 + px * 33 + n] +
                      Pbuf[(t * 2 + 1) * 1056 + px * 33 + n];
            out[rowBase + (size_t)oc * HW + px] = v;
        }
    }
}

// ---------------- center frame passthrough ----------------
__global__ void copy_center_k(const float* __restrict__ x, float* __restrict__ out) {
    int idx = blockIdx.x * 256 + threadIdx.x;  // < 524288 float4s
    int b = idx >> 18;
    int rem = idx & 262143;
    size_t o = (((size_t)(b * TT + TCF) * CC * HW) >> 2) + rem;
    ((float4*)out)[o] = ((const float4*)x)[o];
}

extern "C" void kernel_launch(void* const* d_in, const int* in_sizes, int n_in,
                              void* d_out, int out_size, void* d_ws, size_t ws_size,
                              hipStream_t stream) {
    const float* x = (const float*)d_in[0];
    const float* w_off1 = (const float*)d_in[1];
    const float* b_off1 = (const float*)d_in[2];
    const float* w_off2 = (const float*)d_in[3];
    const float* b_off2 = (const float*)d_in[4];
    const float* w_align1 = (const float*)d_in[5];
    const float* w_alignf = (const float*)d_in[6];
    float* out = (float*)d_out;
    float* ws = (float*)d_ws;

    float* off2 = ws;                        // 4,718,592 floats (NCHW fp32)
    float* off2u = ws + 4718592;             // 18,874,368
    float* off1 = ws + 23592960;             // 18,874,368
    short* z1T = (short*)(ws + 42467328);    // 8,921,088 shorts
    short* xT = (short*)(ws + 46927872);     // 2,230,272 shorts
    short* x2T = (short*)(ws + 48043008);    // 2,787,840 shorts
    short* wsD1 = (short*)(ws + 49436928);   // 36,864 shorts
    short* wsDf = (short*)(ws + 49455360);   // 36,864 shorts
    short* w2s = (short*)(ws + 49473792);    // 184,320 shorts
    short* w1s = (short*)(ws + 49565952);    // 512,000 shorts
    float* xg = ws + 49821952;               // 8,388,608 floats (group-NHWC fp32)

    // zero the padded NHWC plane buffers (z1T, xT, x2T are contiguous)
    hipMemsetAsync((void*)z1T, 0, 27878400, stream);

    wswzD_k<<<144, 256, 0, stream>>>(w_align1, wsD1);
    wswzD_k<<<144, 256, 0, stream>>>(w_alignf, wsDf);
    wswz_k<9><<<720, 256, 0, stream>>>(w_off2, w2s);
    wswz_k<25><<<2000, 256, 0, stream>>>(w_off1, w1s);

    avgpool_k<<<dim3(64, 4, 10), 256, 0, stream>>>(x, x2T);
    xtrans_k<<<dim3(128, 4, 2), 256, 0, stream>>>(x, xT);
    xgt_k<<<dim3(128, 8, 8), 256, 0, stream>>>(x, xg);

    convmf0_k<<<dim3(16, 1, 8), 512, 25344, stream>>>(x2T, w2s, b_off2, off2);
    upsample_k<<<73728, 256, 0, stream>>>(off2, off2u);
    dconv_k<<<dim3(8, 512), 256, 0, stream>>>(xg, off2u, wsD1, nullptr, z1T, 0);
    // LDS: pixels 2*25344 B + weight-slice pieces 2*9216 B = 69120 B -> 2 blocks/CU
    convmf1_k<<<dim3(64, 2, 8), 256, 69120, stream>>>(z1T, xT, w1s, b_off1,
                                                      off2u, off1);
    dconv_k<<<dim3(8, 512), 256, 0, stream>>>(xg, off1, wsDf, out, nullptr, 1);
    copy_center_k<<<2048, 256, 0, stream>>>(x, out);
}

// Round 11
// 470.836 us; speedup vs baseline: 1.0262x; 1.0262x over previous
//
#include <hip/hip_runtime.h>
#include <cstdint>

// Problem constants
#define BB 2
#define TT 5
#define CC 64
#define HH 128
#define WW 128
#define GG 8
#define KKD 9
#define OFFC 144
#define H2 64
#define W2 64
#define TCF 2
#define HW (HH*WW)
#define HW2 (H2*W2)
#define PLANE1 278784  // 132*132*16 shorts (full-res padded NHWC chunk plane)
#define PLANE0 69696   // 66*66*16 shorts (half-res padded NHWC chunk plane)

typedef __attribute__((ext_vector_type(4))) short short4v;
typedef __attribute__((ext_vector_type(8))) short short8;
typedef __attribute__((ext_vector_type(4))) float floatx4;
typedef __attribute__((ext_vector_type(16))) float floatx16;

static __device__ __forceinline__ unsigned short f2bf(float f) {
    unsigned int u = __float_as_uint(f);
    unsigned int r = (u + 0x7fffu + ((u >> 16) & 1u)) >> 16;
    return (unsigned short)r;
}

typedef __attribute__((address_space(1))) const unsigned int g_u32;
typedef __attribute__((address_space(3))) unsigned int l_u32;
static __device__ __forceinline__ void async16(const short* g, short* l) {
    __builtin_amdgcn_global_load_lds((g_u32*)g, (l_u32*)l, 16, 0, 0);
}

// ---------------- dconv weight swizzle into MFMA B-fragment order (bf16) -------------
// layout: [chunk(36)][tile(2)][lane(64)][j(8)]
__global__ void wswzD_k(const float* __restrict__ w, short* __restrict__ ws) {
    int idx = blockIdx.x * 256 + threadIdx.x;
    if (idx >= 36864) return;
    int j = idx & 7;
    int lane = (idx >> 3) & 63;
    int tile = (idx >> 9) & 1;
    int chunk = idx >> 10;
    int ck = chunk * 16 + (lane >> 5) * 8 + j;
    int oc = tile * 32 + (lane & 31);
    int cin = ck / 9;
    int kt = ck - cin * 9;
    ws[idx] = (short)f2bf(w[((size_t)oc * 64 + cin) * 9 + kt]);
}

// ---------------- conv weight swizzle into MFMA fragment order (bf16) ----------------
// layout: [chunk(8)][tap(TAPS)][ocF(5)][lane(64)][j(8)]
template <int TAPS>
__global__ void wswz_k(const float* __restrict__ w, short* __restrict__ ws) {
    int idx = blockIdx.x * 256 + threadIdx.x;
    if (idx >= 8 * TAPS * 5 * 512) return;
    int jj = idx & 7;
    int lane = (idx >> 3) & 63;
    int rest = idx >> 9;
    int ocF = rest % 5;
    int ct = rest / 5;
    int tap = ct % TAPS;
    int chunk = ct / TAPS;
    int oc = ocF * 32 + (lane & 31);
    int cin = chunk * 16 + (lane >> 5) * 8 + jj;
    float v = 0.f;
    if (oc < OFFC) v = w[((size_t)oc * 128 + cin) * TAPS + tap];
    ws[idx] = (short)f2bf(v);
}

// ---------------- 2x2 average pool -> padded NHWC-bf16 chunk planes ----------------
__global__ void avgpool_k(const float* __restrict__ x, short* __restrict__ x2T) {
    __shared__ float sL[64 * 17];
    const int h2 = blockIdx.x;
    const int chunk = blockIdx.y;
    const int img = blockIdx.z;
    const int tid = threadIdx.x;
    const float* base = x + ((size_t)img * 64 + chunk * 16) * HW + (size_t)(2 * h2) * WW;
#pragma unroll
    for (int it = 0; it < 4; ++it) {
        int e = it * 256 + tid;
        int cin = e >> 6, w2 = e & 63;
        const float* sp = base + (size_t)cin * HW + 2 * w2;
        sL[w2 * 17 + cin] = 0.25f * (sp[0] + sp[1] + sp[WW] + sp[WW + 1]);
    }
    __syncthreads();
    int w2 = tid >> 2, cg = tid & 3;
    short4v sv;
#pragma unroll
    for (int q = 0; q < 4; ++q) sv[q] = (short)f2bf(sL[w2 * 17 + cg * 4 + q]);
    *(short4v*)&x2T[((size_t)img * 4 + chunk) * PLANE0 +
                    ((size_t)(h2 + 1) * 66 + (w2 + 1)) * 16 + cg * 4] = sv;
}

// ---------------- center-frame transpose -> padded NHWC-bf16 chunk planes ------------
__global__ void xtrans_k(const float* __restrict__ x, short* __restrict__ xT) {
    __shared__ float sL[128 * 17];
    const int row = blockIdx.x;
    const int chunk = blockIdx.y;
    const int b = blockIdx.z;
    const int tid = threadIdx.x;
    const float* base = x + ((size_t)(b * 5 + TCF) * 64 + chunk * 16) * HW + (size_t)row * WW;
#pragma unroll
    for (int it = 0; it < 8; ++it) {
        int e = it * 256 + tid;
        int cin = e >> 7, col = e & 127;
        sL[col * 17 + cin] = base[(size_t)cin * HW + col];
    }
    __syncthreads();
    int col = tid >> 1, half = tid & 1;
    short8 sv;
#pragma unroll
    for (int q = 0; q < 8; ++q) sv[q] = (short)f2bf(sL[col * 17 + half * 8 + q]);
    *(short8*)&xT[((size_t)b * 4 + chunk) * PLANE1 +
                  ((size_t)(row + 2) * 132 + (col + 2)) * 16 + half * 8] = sv;
}

// ---------------- non-center frames -> group-major NHWC fp32 for dconv gather --------
// xg layout: [bj(8)][g(8)][H*W][8ch] fp32.  One corner sample = 32B contiguous.
__global__ void xgt_k(const float* __restrict__ x, float* __restrict__ xg) {
    __shared__ float sL[128 * 9];
    const int row = blockIdx.x;   // 0..127
    const int g = blockIdx.y;     // 0..7
    const int bj = blockIdx.z;    // 0..7
    const int b = bj >> 2;
    const int j = bj & 3;
    const int i = j + (j >= 2 ? 1 : 0);
    const int tid = threadIdx.x;
    const float* base = x + ((size_t)(b * TT + i) * CC + g * 8) * HW + (size_t)row * WW;
#pragma unroll
    for (int it = 0; it < 4; ++it) {
        int e = it * 256 + tid;
        int cin = e >> 7, col = e & 127;
        sL[col * 9 + cin] = base[(size_t)cin * HW + col];
    }
    __syncthreads();
    int col = tid >> 1, half = tid & 1;
    floatx4 v;
#pragma unroll
    for (int q = 0; q < 4; ++q) v[q] = sL[col * 9 + half * 4 + q];
    *(floatx4*)&xg[(((size_t)(bj * 8 + g) * HW + row * WW + col) << 3) + half * 4] = v;
}

// ---------------- MODE 0: 3x3 half-res conv, round-2 configuration ------------------
static __device__ __forceinline__ void conv0_body(
    const short* __restrict__ srcAT,
    const short* __restrict__ wswz, const float* __restrict__ bias,
    float* __restrict__ out) {
    constexpr int KS = 3;
    constexpr int IM = 64;
    constexpr int PD = IM + KS - 1;
    constexpr int TAPS = KS * KS;
    constexpr int OROWS = 4;
    constexpr int SROWS = OROWS + KS - 1;
    constexpr int PLANE = PD * PD * 16;
    constexpr int SLAB16 = SROWS * PD * 2;
    constexpr int BUFSH = SROWS * PD * 16;

    extern __shared__ __align__(16) short stg[];  // 2 * BUFSH shorts

    const int bj = blockIdx.z;
    const int b = bj >> 2;
    const int j = bj & 3;
    const int i = j + (j >= 2 ? 1 : 0);
    const int y0 = blockIdx.x * OROWS;
    const int tid = threadIdx.x;
    const int wave = tid >> 6;
    const int lane = tid & 63;
    const int l31 = lane & 31;
    const int quad = lane >> 5;
    const int wrb = wave >> 1;
    const int wc0 = (wave & 1) * 32;

    const short* srcA = srcAT + (size_t)((b * 5 + i) * 4) * PLANE;
    const short* srcB = srcAT + (size_t)((b * 5 + TCF) * 4) * PLANE;

    floatx16 acc[5];
#pragma unroll
    for (int o = 0; o < 5; ++o)
#pragma unroll
        for (int g = 0; g < 16; ++g) acc[o][g] = 0.f;

    auto stage = [&](int c, int sIdx) {
        const short* plane = (c < 4) ? (srcA + (size_t)c * PLANE)
                                     : (srcB + (size_t)(c - 4) * PLANE);
        const short* srcRow = plane + (size_t)y0 * (PD * 16);
        short* dst = stg + (size_t)sIdx * BUFSH;
        for (int base = wave * 64; base < SLAB16; base += 512) {
            int b2 = min(base, SLAB16 - 64);
            async16(srcRow + (size_t)(b2 + lane) * 8, dst + (size_t)b2 * 8);
        }
    };

    stage(0, 0);
    for (int c = 0; c < 8; ++c) {
        __syncthreads();
        if (c < 7) stage(c + 1, (c + 1) & 1);
        const short* sbuf = stg + (size_t)(c & 1) * BUFSH;
        const short* wpc = wswz + (size_t)c * TAPS * 2560 + lane * 8;
#pragma unroll 5
        for (int tap = 0; tap < TAPS; ++tap) {
            const int ky = tap / KS, kx = tap - ky * KS;
            short8 wf[5];
            const short* wp = wpc + (size_t)tap * 2560;
#pragma unroll
            for (int o = 0; o < 5; ++o) wf[o] = *(const short8*)(wp + o * 512);
            short8 pf = *(const short8*)(sbuf +
                ((size_t)(wrb + ky) * PD + (wc0 + kx + l31)) * 16 + quad * 8);
#pragma unroll
            for (int o = 0; o < 5; ++o)
                acc[o] = __builtin_amdgcn_mfma_f32_32x32x16_bf16(wf[o], pf, acc[o], 0, 0, 0);
        }
    }

    const size_t imgBase = (size_t)bj * OFFC * (IM * IM);
    const size_t rowAddr = imgBase + (size_t)(y0 + wrb) * IM + wc0 + l31;
#pragma unroll
    for (int o = 0; o < 5; ++o) {
        const int rmax = (o == 4) ? 8 : 16;
#pragma unroll
        for (int r = 0; r < 16; ++r) {
            if (r >= rmax) break;
            int oc = o * 32 + (r & 3) + 8 * (r >> 2) + 4 * quad;
            float v = acc[o][r] + bias[oc];
            out[rowAddr + (size_t)oc * (IM * IM)] = v;
        }
    }
}

__global__ __launch_bounds__(512) void convmf0_k(
    const short* __restrict__ srcAT,
    const short* __restrict__ wswz, const float* __restrict__ bias,
    float* __restrict__ out) {
    conv0_body(srcAT, wswz, bias, out);
}

// ---------------- MODE 1: 5x5 full-res conv, weights in LDS, 2 blocks/CU ------------
// PROVEN round-9 configuration (118 us, MfmaUtil 54.7% on its ~56% LDS-read cap):
// 8 waves x [5 wf + 1 pf] ds_read_b128 per tap vs 40 MFMA -> cap 56%. Attempts to
// raise the cap (FR=2 reg-tiling r4/5/6, o-split r10, hybrid-global r8) all failed:
// allocator wall at VGPR+AGPR>256, occupancy wall at 256-thr blocks, vmcnt
// serialization. This dataflow's ceiling. Weights staged in 9 pieces of <=3 taps;
// LDS = 50688 pixel dbuf + 30720 weight dbuf = 81408 B -> 2 blocks/CU.
__global__ __launch_bounds__(512) void convmf1_k(
    const short* __restrict__ srcAT, const short* __restrict__ srcBT,
    const short* __restrict__ wswz, const float* __restrict__ bias,
    const float* __restrict__ addend, float* __restrict__ out) {
    constexpr int KS = 5;
    constexpr int IM = 128;
    constexpr int PD = IM + KS - 1;          // 132
    constexpr int OROWS = 2;
    constexpr int SROWS = OROWS + KS - 1;    // 6
    constexpr int PLANE = PD * PD * 16;
    constexpr int SLAB16 = SROWS * PD * 2;   // 1584 16B-units
    constexpr int BUFSH = SROWS * PD * 16;   // 12672 shorts per pixel buffer
    constexpr int WP = 3 * 2560;             // 7680 shorts per weight piece (<=3 taps)

    extern __shared__ __align__(16) short lds[];  // 2*BUFSH + 2*WP shorts = 81408 B
    short* pbuf = lds;
    short* wbuf = lds + 2 * BUFSH;

    const int bj = blockIdx.z;
    const int b = bj >> 2;
    const int y0 = blockIdx.x * OROWS;
    const int tid = threadIdx.x;
    const int wave = tid >> 6;
    const int lane = tid & 63;
    const int l31 = lane & 31;
    const int quad = lane >> 5;
    const int wrb = wave >> 2;             // row 0..1
    const int wc0 = (wave & 3) * 32;       // col tile

    const short* srcA = srcAT + (size_t)(bj * 4) * PLANE;
    const short* srcB = srcBT + (size_t)(b * 4) * PLANE;

    floatx16 acc[5];
#pragma unroll
    for (int o = 0; o < 5; ++o)
#pragma unroll
        for (int g = 0; g < 16; ++g) acc[o][g] = 0.f;

    auto stageP = [&](int c, int sIdx) {
        const short* plane = (c < 4) ? (srcA + (size_t)c * PLANE)
                                     : (srcB + (size_t)(c - 4) * PLANE);
        const short* srcRow = plane + (size_t)y0 * (PD * 16);
        short* dst = pbuf + (size_t)sIdx * BUFSH;
        for (int base = wave * 64; base < SLAB16; base += 512) {
            int b2 = min(base, SLAB16 - 64);
            async16(srcRow + (size_t)(b2 + lane) * 8, dst + (size_t)b2 * 8);
        }
    };
    // stage taps [qoff, qoff+qn) of chunk c into wbuf half sIdx (contiguous copy).
    auto stageW = [&](int c, int qoff, int qn, int sIdx) {
        const short* src = wswz + (size_t)c * 64000 + (size_t)qoff * 2560;
        short* dst = wbuf + (size_t)sIdx * WP;
        const int n16 = qn * 320;  // 16B units
        for (int base = wave * 64; base < n16; base += 512) {
            int b2 = min(base, n16 - 64);
            async16(src + (size_t)(b2 + lane) * 8, dst + (size_t)b2 * 8);
        }
    };

    constexpr int NP = 9;
    constexpr int QOFF[NP] = {0, 3, 6, 9, 12, 15, 18, 21, 24};
    constexpr int QN[NP] = {3, 3, 3, 3, 3, 3, 3, 3, 1};

    stageP(0, 0);
    stageW(0, 0, 3, 0);
    for (int c = 0; c < 8; ++c) {
#pragma unroll
        for (int q = 0; q < NP; ++q) {
            __syncthreads();  // wbuf[(c+q)&1] ready; other half free; q0: pbuf[c&1] ready
            const int pb = (c + q) & 1;  // piece parity (NP odd -> alternates cleanly)
            // issue next piece's weight stage (overlaps with this piece's MFMA)
            if (!(c == 7 && q == NP - 1)) {
                const int nc = (q == NP - 1) ? c + 1 : c;
                const int nq = (q == NP - 1) ? 0 : q + 1;
                stageW(nc, QOFF[nq], QN[nq], pb ^ 1);
            }
            if (q == 0 && c < 7) stageP(c + 1, (c + 1) & 1);
            const short* sbuf = pbuf + (size_t)(c & 1) * BUFSH;
            const short* wb = wbuf + (size_t)pb * WP + lane * 8;
#pragma unroll
            for (int t = 0; t < QN[q]; ++t) {
                const int tap = QOFF[q] + t;
                const int ky = tap / KS, kx = tap - ky * KS;
                short8 wf[5];
#pragma unroll
                for (int o = 0; o < 5; ++o)
                    wf[o] = *(const short8*)(wb + (t * 5 + o) * 512);
                short8 pf = *(const short8*)(sbuf +
                    ((size_t)(wrb + ky) * PD + (wc0 + kx + l31)) * 16 + quad * 8);
#pragma unroll
                for (int o = 0; o < 5; ++o)
                    acc[o] = __builtin_amdgcn_mfma_f32_32x32x16_bf16(wf[o], pf,
                                                                     acc[o], 0, 0, 0);
            }
        }
    }

    const size_t imgBase = (size_t)bj * OFFC * (IM * IM);
    const size_t rowAddr = imgBase + (size_t)(y0 + wrb) * IM + wc0 + l31;
#pragma unroll
    for (int o = 0; o < 5; ++o) {
        const int rmax = (o == 4) ? 8 : 16;
#pragma unroll
        for (int r = 0; r < 16; ++r) {
            if (r >= rmax) break;
            int oc = o * 32 + (r & 3) + 8 * (r >> 2) + 4 * quad;
            float v = acc[o][r] + bias[oc];
            size_t a = rowAddr + (size_t)oc * (IM * IM);
            out[a] = v + addend[a];
        }
    }
}

// ---------------- bilinear 2x upsample * 2.0 ----------------
__global__ void upsample_k(const float* __restrict__ off2, float* __restrict__ off2u) {
    int idx = blockIdx.x * 256 + threadIdx.x;  // < 18874368
    int ox = idx & 127;
    int oy = (idx >> 7) & 127;
    int p = idx >> 14;
    const float* sp = off2 + (size_t)p * HW2;
    float sy = 0.5f * oy - 0.25f;
    float sx = 0.5f * ox - 0.25f;
    float y0f = floorf(sy), x0f = floorf(sx);
    int y0 = (int)y0f, x0 = (int)x0f;
    float fy = sy - y0f, fx = sx - x0f;
    int y0c = max(y0, 0), y1c = min(y0 + 1, 63);
    int x0c = max(x0, 0), x1c = min(x0 + 1, 63);
    float v00 = sp[y0c * 64 + x0c], v01 = sp[y0c * 64 + x1c];
    float v10 = sp[y1c * 64 + x0c], v11 = sp[y1c * 64 + x1c];
    float v = v00 * (1.f - fy) * (1.f - fx) + v01 * (1.f - fy) * fx +
              v10 * fy * (1.f - fx) + v11 * fy * fx;
    off2u[idx] = 2.0f * v;
}

// ---------------- deformable conv (3x3, G=8 offset groups), MFMA phase B -------------
// 512-thr blocks (8 waves) per 32-px row segment. TA-coalescing restructure: lane =
// (px*2 + chhalf) within one g per wave -> adjacent lane PAIRS read the two 16B
// halves of the SAME 32B corner, and the wave's 32 px cluster in-row -> distinct
// cache-line regions per load instruction halve vs the (2g x 32px) layout. Loads per
// thread halve (36 corner float4s); 8 waves x 4 blocks/CU = 32 waves/CU (2x latency
// hiding vs the 256-thr version). Phase B: K split 4 ways across 8 waves
// (tile = wv&1, kq = wv>>1, 9 chunks each); Pbuf 8x1056 fl = 33792 B fits sS.
#define SROW 584
__global__ __launch_bounds__(512) void dconv_k(
    const float* __restrict__ xg,   // (8 imgs, G, H*W, 8ch) fp32
    const float* __restrict__ off,  // (BJ,144,H,W)
    const short* __restrict__ wsw,  // swizzled B-frags [chunk36][tile2][lane64][8]
    float* __restrict__ out, short* __restrict__ z1T, int outMode) {
    const int bj = blockIdx.x;   // image -> XCD (round-robin by linear block ID)
    const int b = bj >> 2;
    const int j = bj & 3;
    const int i = j + (j >= 2 ? 1 : 0);
    const int seg = blockIdx.y;  // 0..511
    const int y = seg >> 2;
    const int x0 = (seg & 3) << 5;
    const int tid = threadIdx.x;

    __shared__ short sS[32 * SROW];  // 37376 B; reused as float Pbuf[8][32][33]
    float* Pbuf = (float*)sS;

    const float* offp = off + (size_t)bj * OFFC * HW + y * WW + x0;

    // ---- phase A: bilinear sampling into LDS (lane pairs share a 32B corner) ----
    {
        const int h = tid & 1;          // channel half (0: ch0-3, 1: ch4-7)
        const int px = (tid >> 1) & 31;
        const int g = tid >> 6;         // one group per wave
        short* srow = sS + px * SROW + g * 72 + h * 36;   // (h*4+c)*9 = h*36 + c*9
        const float* xgp = xg + ((size_t)(bj * 8 + g)) * ((size_t)HW * 8) + h * 4;
        const float* offg = offp + (size_t)(g * 18) * HW + px;
#pragma unroll 1
        for (int kg = 0; kg < 3; ++kg) {
            const int kyy = kg - 1;
            const float fyrow = (float)(y + kyy);
#pragma unroll
            for (int kk = 0; kk < 3; ++kk) {
                const int k = kg * 3 + kk;
                float dy = offg[(size_t)(k * 2) * HW];
                float dx = offg[(size_t)(k * 2 + 1) * HW];
                const int kxx = kk - 1;
                float sy = fyrow + dy;
                float sx = (float)(x0 + px + kxx) + dx;
                float y0f = floorf(sy), x0f = floorf(sx);
                int iy = (int)y0f, ix = (int)x0f;
                float wy = sy - y0f, wx = sx - x0f;
                bool yv0 = (iy >= 0) & (iy < HH);
                bool yv1 = (iy + 1 >= 0) & (iy + 1 < HH);
                bool xv0 = (ix >= 0) & (ix < WW);
                bool xv1 = (ix + 1 >= 0) & (ix + 1 < WW);
                float w00 = (yv0 && xv0) ? (1.f - wy) * (1.f - wx) : 0.f;
                float w01 = (yv0 && xv1) ? (1.f - wy) * wx : 0.f;
                float w10 = (yv1 && xv0) ? wy * (1.f - wx) : 0.f;
                float w11 = (yv1 && xv1) ? wy * wx : 0.f;
                int iy0 = min(max(iy, 0), HH - 1);
                int iy1 = min(max(iy + 1, 0), HH - 1);
                int ix0 = min(max(ix, 0), WW - 1);
                int ix1 = min(max(ix + 1, 0), WW - 1);
                floatx4 a00 = *(const floatx4*)(xgp + ((size_t)(iy0 * WW + ix0) << 3));
                floatx4 a01 = *(const floatx4*)(xgp + ((size_t)(iy0 * WW + ix1) << 3));
                floatx4 a10 = *(const floatx4*)(xgp + ((size_t)(iy1 * WW + ix0) << 3));
                floatx4 a11 = *(const floatx4*)(xgp + ((size_t)(iy1 * WW + ix1) << 3));
#pragma unroll
                for (int c = 0; c < 4; ++c) {
                    float v = a00[c] * w00 + a01[c] * w01 + a10[c] * w10 + a11[c] * w11;
                    srow[c * 9 + k] = (short)f2bf(v);
                }
            }
        }
    }
    __syncthreads();

    // ---- phase B: C[px 32][oc 64] = S * W, K=576 split 4 ways, MFMA 32x32x16 ----
    const int wv = tid >> 6;      // wave 0..7
    const int lane = tid & 63;
    const int tile = wv & 1;      // oc tile
    const int kq = wv >> 1;       // K quarter (9 chunks)
    floatx16 acc;
#pragma unroll
    for (int g = 0; g < 16; ++g) acc[g] = 0.f;

    const short* aBase = sS + (lane & 31) * SROW + (lane >> 5) * 8;
    const short* bBase = wsw + ((size_t)tile * 64 + lane) * 8;
    for (int chunk = kq * 9; chunk < kq * 9 + 9; ++chunk) {
        short8 af = *(const short8*)(aBase + chunk * 16);
        short8 bf = *(const short8*)(bBase + (size_t)chunk * 1024);
        acc = __builtin_amdgcn_mfma_f32_32x32x16_bf16(af, bf, acc, 0, 0, 0);
    }

    __syncthreads();  // all waves done reading sS; alias as Pbuf
    {
        const int n = lane & 31;
#pragma unroll
        for (int g = 0; g < 16; ++g) {
            int m = (g & 3) + 8 * (g >> 2) + 4 * (lane >> 5);
            Pbuf[wv * 1056 + m * 33 + n] = acc[g];
        }
    }
    __syncthreads();

    // ---- epilogue: reduce K-quarters, store ----
    if (outMode == 0) {
        if (tid < 256) {
            const int chunk = tid >> 6;
            const int px = (tid >> 1) & 31;
            const int half = tid & 1;
            const int t2 = chunk >> 1;
            const int n0 = (chunk & 1) * 16 + half * 8;
            short8 sv;
#pragma unroll
            for (int q = 0; q < 8; ++q) {
                float v = Pbuf[(0 * 2 + t2) * 1056 + px * 33 + n0 + q] +
                          Pbuf[(1 * 2 + t2) * 1056 + px * 33 + n0 + q] +
                          Pbuf[(2 * 2 + t2) * 1056 + px * 33 + n0 + q] +
                          Pbuf[(3 * 2 + t2) * 1056 + px * 33 + n0 + q];
                sv[q] = (short)f2bf(v);
            }
            *(short8*)&z1T[((size_t)bj * 4 + chunk) * PLANE1 +
                           ((size_t)(y + 2) * 132 + (x0 + 2 + px)) * 16 + half * 8] = sv;
        }
    } else {
        const size_t planeBase = (size_t)(b * TT + i) * CC * HW;
        const size_t rowBase = planeBase + (size_t)y * WW + x0;
#pragma unroll
        for (int rep = 0; rep < 4; ++rep) {
            int elem = rep * 512 + tid;
            int oc = elem >> 5;
            int px = elem & 31;
            int t = oc >> 5;
            int n = oc & 31;
            float v = Pbuf[(0 * 2 + t) * 1056 + px * 33 + n] +
                      Pbuf[(1 * 2 + t) * 1056 + px * 33 + n] +
                      Pbuf[(2 * 2 + t) * 1056 + px * 33 + n] +
                      Pbuf[(3 * 2 + t) * 1056 + px * 33 + n];
            out[rowBase + (size_t)oc * HW + px] = v;
        }
    }
}

// ---------------- center frame passthrough ----------------
__global__ void copy_center_k(const float* __restrict__ x, float* __restrict__ out) {
    int idx = blockIdx.x * 256 + threadIdx.x;  // < 524288 float4s
    int b = idx >> 18;
    int rem = idx & 262143;
    size_t o = (((size_t)(b * TT + TCF) * CC * HW) >> 2) + rem;
    ((float4*)out)[o] = ((const float4*)x)[o];
}

extern "C" void kernel_launch(void* const* d_in, const int* in_sizes, int n_in,
                              void* d_out, int out_size, void* d_ws, size_t ws_size,
                              hipStream_t stream) {
    const float* x = (const float*)d_in[0];
    const float* w_off1 = (const float*)d_in[1];
    const float* b_off1 = (const float*)d_in[2];
    const float* w_off2 = (const float*)d_in[3];
    const float* b_off2 = (const float*)d_in[4];
    const float* w_align1 = (const float*)d_in[5];
    const float* w_alignf = (const float*)d_in[6];
    float* out = (float*)d_out;
    float* ws = (float*)d_ws;

    float* off2 = ws;                        // 4,718,592 floats (NCHW fp32)
    float* off2u = ws + 4718592;             // 18,874,368
    float* off1 = ws + 23592960;             // 18,874,368
    short* z1T = (short*)(ws + 42467328);    // 8,921,088 shorts
    short* xT = (short*)(ws + 46927872);     // 2,230,272 shorts
    short* x2T = (short*)(ws + 48043008);    // 2,787,840 shorts
    short* wsD1 = (short*)(ws + 49436928);   // 36,864 shorts
    short* wsDf = (short*)(ws + 49455360);   // 36,864 shorts
    short* w2s = (short*)(ws + 49473792);    // 184,320 shorts
    short* w1s = (short*)(ws + 49565952);    // 512,000 shorts
    float* xg = ws + 49821952;               // 8,388,608 floats (group-NHWC fp32)

    // zero the padded NHWC plane buffers (z1T, xT, x2T are contiguous)
    hipMemsetAsync((void*)z1T, 0, 27878400, stream);

    wswzD_k<<<144, 256, 0, stream>>>(w_align1, wsD1);
    wswzD_k<<<144, 256, 0, stream>>>(w_alignf, wsDf);
    wswz_k<9><<<720, 256, 0, stream>>>(w_off2, w2s);
    wswz_k<25><<<2000, 256, 0, stream>>>(w_off1, w1s);

    avgpool_k<<<dim3(64, 4, 10), 256, 0, stream>>>(x, x2T);
    xtrans_k<<<dim3(128, 4, 2), 256, 0, stream>>>(x, xT);
    xgt_k<<<dim3(128, 8, 8), 256, 0, stream>>>(x, xg);

    convmf0_k<<<dim3(16, 1, 8), 512, 25344, stream>>>(x2T, w2s, b_off2, off2);
    upsample_k<<<73728, 256, 0, stream>>>(off2, off2u);
    dconv_k<<<dim3(8, 512), 512, 0, stream>>>(xg, off2u, wsD1, nullptr, z1T, 0);
    // LDS: pixels 2*25344 B + weight pieces 2*15360 B = 81408 B -> 2 blocks/CU
    convmf1_k<<<dim3(64, 1, 8), 512, 81408, stream>>>(z1T, xT, w1s, b_off1,
                                                      off2u, off1);
    dconv_k<<<dim3(8, 512), 512, 0, stream>>>(xg, off1, wsDf, out, nullptr, 1);
    copy_center_k<<<2048, 256, 0, stream>>>(x, out);
}